// Round 5
// baseline (29.135 us; speedup 1.0000x reference)
//
#include <hip/hip_runtime.h>
#include <hip/hip_bf16.h>

// CoarseGrain: avg-pool SCALE=4 over last dim of (128, 4, 65536) fp32.
// out[n,c,l] = mean(x[n,c,4l:4l+4]).  Memory-bound streaming kernel.
//
// Wave-dense loads (R4 structure, best so far: 28.93 us). This round:
// non-temporal STORES only — output has zero reuse, skip L2
// write-allocate. Loads stay cached (R3: nt loads regressed 42%).

typedef float v4f __attribute__((ext_vector_type(4)));

__global__ __launch_bounds__(256) void CoarseGrain_26474178413228_kernel(
    const float* __restrict__ x, float* __restrict__ out) {
    const v4f* __restrict__ in4 = reinterpret_cast<const v4f*>(x);

    // Each block handles 1024 consecutive float4 inputs (16 KB) ->
    // 1024 consecutive float outputs (4 KB).
    int base = blockIdx.x * 1024 + threadIdx.x;  // in float4 / float units

    v4f a = in4[base + 0 * 256];
    v4f b = in4[base + 1 * 256];
    v4f c = in4[base + 2 * 256];
    v4f d = in4[base + 3 * 256];

    __builtin_nontemporal_store((a.x + a.y + a.z + a.w) * 0.25f, &out[base + 0 * 256]);
    __builtin_nontemporal_store((b.x + b.y + b.z + b.w) * 0.25f, &out[base + 1 * 256]);
    __builtin_nontemporal_store((c.x + c.y + c.z + c.w) * 0.25f, &out[base + 2 * 256]);
    __builtin_nontemporal_store((d.x + d.y + d.z + d.w) * 0.25f, &out[base + 3 * 256]);
}

extern "C" void kernel_launch(void* const* d_in, const int* in_sizes, int n_in,
                              void* d_out, int out_size, void* d_ws, size_t ws_size,
                              hipStream_t stream) {
    const float* x = (const float*)d_in[0];
    float* out = (float*)d_out;

    // out_size = 8,388,608 floats; each block produces 1024 outputs.
    int grid = out_size / 1024;  // = 8192, exact

    CoarseGrain_26474178413228_kernel<<<grid, 256, 0, stream>>>(x, out);
}